// Round 5
// baseline (487.570 us; speedup 1.0000x reference)
//
#include <hip/hip_runtime.h>
#include <hip/hip_bf16.h>

// Problem constants
#define BATCH 32
#define LQ 64
#define LD 512
#define EMB 300
#define FFH 100
#define ATTD 32
#define NH 8
#define NK 21
#define MQ (BATCH * LQ)          // 2048 query tokens
#define MD (BATCH * LD)          // 16384 doc tokens
#define MALL (MQ + MD)           // 18432 merged tokens

__device__ __forceinline__ float wave_sum(float v) {
    #pragma unroll
    for (int off = 32; off > 0; off >>= 1) v += __shfl_xor(v, off);
    return v;
}

// ---------------- elementwise: x = emb * mask(token) ----------------
__global__ void maskmul_kernel(const float* __restrict__ emb, const float* __restrict__ mask,
                               float* __restrict__ out, int n) {
    int i = blockIdx.x * blockDim.x + threadIdx.x;
    if (i < n) out[i] = emb[i] * mask[i / EMB];
}

// ---------------- mask concat: [mask_q | mask_d] -> maskall[18432] ----------------
__global__ void maskcat_kernel(const float* __restrict__ mq, const float* __restrict__ md,
                               float* __restrict__ out) {
    int i = blockIdx.x * blockDim.x + threadIdx.x;
    if (i < MALL) out[i] = (i < MQ) ? mq[i] : md[i - MQ];
}

// ---------------- tiled GEMM v2: 32x64 tile, double-buffered LDS, 1 barrier/K-step --------
// C[M,N] = A[M,K] @ B[K,N] + bias (+relu / +residual)
// EPI: 0 = bias, 1 = bias+relu, 2 = bias+residual
// Block 256 threads: thread (tr,tc) computes rows m0+2tr..+1, cols n0+4tc..+3.
// M must be a multiple of 32; N,K arbitrary (N%4==0 assumed for stores).
template <int EPI>
__global__ __launch_bounds__(256) void gemm_nn(const float* __restrict__ A, const float* __restrict__ Bw,
                                               const float* __restrict__ bias, const float* __restrict__ R,
                                               float* __restrict__ C, int M, int N, int K) {
    __shared__ __align__(16) float As[2][16][32];   // [buf][k][m]
    __shared__ __align__(16) float Bs[2][16][64];   // [buf][k][n]
    const int tid = threadIdx.x;
    const int m0 = blockIdx.y * 32, n0 = blockIdx.x * 64;
    const int tr = tid >> 4, tc = tid & 15;         // tr,tc in [0,16)
    const int rA = tid >> 2, kA = (tid & 3) * 4;    // A staging (tid<128): 32 rows x 16 k
    const bool nfull = (n0 + 64 <= N);
    const int NS = (K + 15) >> 4;

    float acc00 = 0.f, acc01 = 0.f, acc02 = 0.f, acc03 = 0.f;
    float acc10 = 0.f, acc11 = 0.f, acc12 = 0.f, acc13 = 0.f;
    float4 av, bv;

#define GEMM_LOAD(K0)                                                           \
    {                                                                           \
        const int k0_ = (K0);                                                   \
        if (tid < 128) {                                                        \
            int kk = k0_ + kA;                                                  \
            const float* arow = A + (size_t)(m0 + rA) * K + kk;                 \
            if (kk + 4 <= K) av = *(const float4*)arow;                         \
            else {                                                              \
                av.x = (kk     < K) ? arow[0] : 0.f;                            \
                av.y = (kk + 1 < K) ? arow[1] : 0.f;                            \
                av.z = (kk + 2 < K) ? arow[2] : 0.f;                            \
                av.w = (kk + 3 < K) ? arow[3] : 0.f;                            \
            }                                                                   \
        }                                                                       \
        int kb = k0_ + tr;                                                      \
        bv.x = bv.y = bv.z = bv.w = 0.f;                                        \
        if (kb < K) {                                                           \
            const float* brow = Bw + (size_t)kb * N + n0 + tc * 4;              \
            if (nfull) bv = *(const float4*)brow;                               \
            else {                                                              \
                int n = n0 + tc * 4;                                            \
                if (n     < N) bv.x = brow[0];                                  \
                if (n + 1 < N) bv.y = brow[1];                                  \
                if (n + 2 < N) bv.z = brow[2];                                  \
                if (n + 3 < N) bv.w = brow[3];                                  \
            }                                                                   \
        }                                                                       \
    }

#define GEMM_STORE_LDS(BUF)                                                     \
    {                                                                           \
        const int b_ = (BUF);                                                   \
        if (tid < 128) {                                                        \
            As[b_][kA + 0][rA] = av.x;                                          \
            As[b_][kA + 1][rA] = av.y;                                          \
            As[b_][kA + 2][rA] = av.z;                                          \
            As[b_][kA + 3][rA] = av.w;                                          \
        }                                                                       \
        *(float4*)&Bs[b_][tr][tc * 4] = bv;                                     \
    }

    GEMM_LOAD(0)
    GEMM_STORE_LDS(0)
    __syncthreads();

    for (int s = 0; s < NS; s++) {
        const int cur = s & 1;
        const bool more = (s + 1 < NS);
        if (more) GEMM_LOAD((s + 1) << 4)
        #pragma unroll
        for (int kk = 0; kk < 16; kk++) {
            float2 a2 = *(const float2*)&As[cur][kk][tr * 2];
            float4 b4 = *(const float4*)&Bs[cur][kk][tc * 4];
            acc00 = fmaf(a2.x, b4.x, acc00);
            acc01 = fmaf(a2.x, b4.y, acc01);
            acc02 = fmaf(a2.x, b4.z, acc02);
            acc03 = fmaf(a2.x, b4.w, acc03);
            acc10 = fmaf(a2.y, b4.x, acc10);
            acc11 = fmaf(a2.y, b4.y, acc11);
            acc12 = fmaf(a2.y, b4.z, acc12);
            acc13 = fmaf(a2.y, b4.w, acc13);
        }
        if (more) GEMM_STORE_LDS(cur ^ 1)
        __syncthreads();
    }
#undef GEMM_LOAD
#undef GEMM_STORE_LDS

    // epilogue
    const int col = n0 + tc * 4;
    float4 bias4 = {0.f, 0.f, 0.f, 0.f};
    if (nfull) bias4 = *(const float4*)(bias + col);
    else {
        if (col     < N) bias4.x = bias[col];
        if (col + 1 < N) bias4.y = bias[col + 1];
        if (col + 2 < N) bias4.z = bias[col + 2];
        if (col + 3 < N) bias4.w = bias[col + 3];
    }
    #pragma unroll
    for (int i = 0; i < 2; i++) {
        int row = m0 + tr * 2 + i;
        float4 v;
        v.x = (i == 0 ? acc00 : acc10) + bias4.x;
        v.y = (i == 0 ? acc01 : acc11) + bias4.y;
        v.z = (i == 0 ? acc02 : acc12) + bias4.z;
        v.w = (i == 0 ? acc03 : acc13) + bias4.w;
        if (EPI == 1) {
            v.x = fmaxf(v.x, 0.f); v.y = fmaxf(v.y, 0.f);
            v.z = fmaxf(v.z, 0.f); v.w = fmaxf(v.w, 0.f);
        }
        if (EPI == 2) {
            const float* rrow = R + (size_t)row * N + col;
            if (nfull) {
                float4 r4 = *(const float4*)rrow;
                v.x += r4.x; v.y += r4.y; v.z += r4.z; v.w += r4.w;
            } else {
                if (col     < N) v.x += rrow[0];
                if (col + 1 < N) v.y += rrow[1];
                if (col + 2 < N) v.z += rrow[2];
                if (col + 3 < N) v.w += rrow[3];
            }
        }
        float* crow = C + (size_t)row * N + col;
        if (nfull) {
            *(float4*)crow = v;
        } else {
            if (col     < N) crow[0] = v.x;
            if (col + 1 < N) crow[1] = v.y;
            if (col + 2 < N) crow[2] = v.z;
            if (col + 3 < N) crow[3] = v.w;
        }
    }
}

// ---------------- LayerNorm (ddof=1, eps added to std), one wave per token (300 elems) ------
__global__ __launch_bounds__(256) void ln_kernel(const float* __restrict__ X, const float* __restrict__ g,
                                                 const float* __restrict__ bta, float* __restrict__ Y, int M) {
    int wid = (blockIdx.x * 256 + threadIdx.x) >> 6;
    int lane = threadIdx.x & 63;
    if (wid >= M) return;
    const float* x = X + (size_t)wid * EMB;
    float v[5];
    float s = 0.f;
    #pragma unroll
    for (int r = 0; r < 5; r++) {
        int idx = lane + r * 64;
        float val = (idx < EMB) ? x[idx] : 0.f;
        v[r] = val;
        s += val;
    }
    s = wave_sum(s);
    float mean = s * (1.f / EMB);
    float s2 = 0.f;
    #pragma unroll
    for (int r = 0; r < 5; r++) {
        int idx = lane + r * 64;
        if (idx < EMB) { float d = v[r] - mean; s2 += d * d; }
    }
    s2 = wave_sum(s2);
    float stdv = sqrtf(s2 * (1.f / (EMB - 1)));
    float inv = 1.f / (stdv + 1e-6f);
    float* y = Y + (size_t)wid * EMB;
    #pragma unroll
    for (int r = 0; r < 5; r++) {
        int idx = lane + r * 64;
        if (idx < EMB) y[idx] = g[idx] * (v[r] - mean) * inv + bta[idx];
    }
}

// ---------------- attention: single-pass (no max), premasked K/V in LDS, k-split ---------
// c layout: [tokens, 96]  (q | k | v, each 32 = 8 heads * 4)
template <int T, int RPB, int KS>
__global__ __launch_bounds__(512) void attn_fused(const float* __restrict__ c,
                                                  const float* __restrict__ mask,
                                                  float* __restrict__ o32) {
    constexpr int BLK = RPB * KS;
    constexpr int NRB = T / RPB;
    __shared__ float4 Ks[T];
    __shared__ float4 Vs[T];
    __shared__ float part[RPB * 5 * (KS - 1)];
    __shared__ float nmask_s;
    const int bh = blockIdx.x / NRB;
    const int rb = blockIdx.x % NRB;
    const int b = bh / NH, h = bh % NH;
    const int tid = threadIdx.x;
    const float* base = c + (size_t)b * T * 96;

    if (tid == 0) nmask_s = 0.f;
    __syncthreads();
    float lnm = 0.f;
    for (int j = tid; j < T; j += BLK) {
        float m = mask[b * T + j];
        float4 kv = *(const float4*)(base + (size_t)j * 96 + ATTD + h * 4);
        float4 vv = *(const float4*)(base + (size_t)j * 96 + 2 * ATTD + h * 4);
        kv.x *= m; kv.y *= m; kv.z *= m; kv.w *= m;
        vv.x *= m; vv.y *= m; vv.z *= m; vv.w *= m;
        Ks[j] = kv;
        Vs[j] = vv;
        lnm += 1.f - m;
    }
    lnm = wave_sum(lnm);
    if ((tid & 63) == 0 && lnm != 0.f) atomicAdd(&nmask_s, lnm);
    __syncthreads();

    const int r = rb * RPB + (tid % RPB);
    const int ks = tid / RPB;
    const float inv_scale = 0.16439898730535729f;  // 1/sqrt(37)
    float4 qv = *(const float4*)(base + (size_t)r * 96 + h * 4);
    qv.x *= inv_scale; qv.y *= inv_scale; qv.z *= inv_scale; qv.w *= inv_scale;

    float Sall = 0.f, ox = 0.f, oy = 0.f, oz = 0.f, ow = 0.f;
    constexpr int KC = T / KS;
    const int k0 = ks * KC;
    #pragma unroll 4
    for (int k = k0; k < k0 + KC; k++) {
        float4 kv = Ks[k];
        float4 vv = Vs[k];
        float s = fmaf(qv.x, kv.x, fmaf(qv.y, kv.y, fmaf(qv.z, kv.z, qv.w * kv.w)));
        float e = __expf(s);
        Sall += e;
        ox = fmaf(e, vv.x, ox);
        oy = fmaf(e, vv.y, oy);
        oz = fmaf(e, vv.z, oz);
        ow = fmaf(e, vv.w, ow);
    }
    if (ks > 0) {
        float* p = &part[((ks - 1) * RPB + (tid % RPB)) * 5];
        p[0] = Sall; p[1] = ox; p[2] = oy; p[3] = oz; p[4] = ow;
    }
    __syncthreads();
    if (ks == 0) {
        #pragma unroll
        for (int s2 = 0; s2 < KS - 1; s2++) {
            const float* p = &part[(s2 * RPB + r - rb * RPB) * 5];
            Sall += p[0]; ox += p[1]; oy += p[2]; oz += p[3]; ow += p[4];
        }
        float Sm = Sall - nmask_s;
        float inv = 1.f / (Sm + 1e-13f * Sall);
        float4 o = {ox * inv, oy * inv, oz * inv, ow * inv};
        *(float4*)(o32 + (size_t)(b * T + r) * ATTD + h * 4) = o;
    }
}

// ---------------- mix + L2 normalize: one wave per token (merged stream) ----------------
__global__ __launch_bounds__(256) void mixnorm_kernel(const float* __restrict__ x, const float* __restrict__ xc,
                                                      const float* __restrict__ mask, const float* __restrict__ mixer,
                                                      float* __restrict__ out) {
    int wid = (blockIdx.x * 256 + threadIdx.x) >> 6;
    int lane = threadIdx.x & 63;
    float mixv = mixer[0];
    float mval = mask[wid];
    const float* xr = x + (size_t)wid * EMB;
    const float* xcr = xc + (size_t)wid * EMB;
    float v[5];
    float s2 = 0.f;
    #pragma unroll
    for (int r = 0; r < 5; r++) {
        int idx = lane + r * 64;
        float val = 0.f;
        if (idx < EMB) val = (mixv * xr[idx] + (1.f - mixv) * xcr[idx]) * mval;
        v[r] = val;
        s2 += val * val;
    }
    s2 = wave_sum(s2);
    float inv = 1.f / (sqrtf(s2) + 1e-13f);
    float* o = out + (size_t)wid * EMB;
    #pragma unroll
    for (int r = 0; r < 5; r++) {
        int idx = lane + r * 64;
        if (idx < EMB) o[idx] = v[r] * inv;
    }
}

// ---------------- batched NT GEMM: cos[b] = qn[b] (64x300) @ dn[b]^T (300x512) ----------------
__global__ __launch_bounds__(256) void gemm_nt_cos(const float* __restrict__ Qn, const float* __restrict__ Dn,
                                                   float* __restrict__ Cos) {
    int b = blockIdx.y;
    int n0 = blockIdx.x * 64;
    const float* A = Qn + (size_t)b * LQ * EMB;
    const float* Bm = Dn + (size_t)b * LD * EMB;
    __shared__ __align__(16) float As[16][68];
    __shared__ __align__(16) float Bs[16][68];
    const int tid = threadIdx.x;
    const int tr = tid >> 4, tc = tid & 15;
    float acc[4][4] = {};
    for (int k0 = 0; k0 < EMB; k0 += 16) {
        #pragma unroll
        for (int i = 0; i < 4; i++) {
            int idx = tid + i * 256;
            int r = idx >> 4, cl = idx & 15;
            int kk = k0 + cl;
            As[cl][r] = (kk < EMB) ? A[(size_t)r * EMB + kk] : 0.f;
            Bs[cl][r] = (kk < EMB) ? Bm[(size_t)(n0 + r) * EMB + kk] : 0.f;
        }
        __syncthreads();
        #pragma unroll
        for (int kk = 0; kk < 16; kk++) {
            float4 a4 = *(const float4*)&As[kk][tr * 4];
            float4 b4 = *(const float4*)&Bs[kk][tc * 4];
            float av[4] = {a4.x, a4.y, a4.z, a4.w};
            float bv[4] = {b4.x, b4.y, b4.z, b4.w};
            #pragma unroll
            for (int i = 0; i < 4; i++)
                #pragma unroll
                for (int j = 0; j < 4; j++) acc[i][j] += av[i] * bv[j];
        }
        __syncthreads();
    }
    #pragma unroll
    for (int i = 0; i < 4; i++) {
        int row = tr * 4 + i;
        #pragma unroll
        for (int j = 0; j < 4; j++) {
            int col = n0 + tc * 4 + j;
            Cos[(size_t)b * LQ * LD + (size_t)row * LD + col] = acc[i][j];
        }
    }
}

// ---------------- kernel pooling: one wave per (b, qi); 21 RBF kernels ----------------
__global__ __launch_bounds__(256) void pool_kernel(const float* __restrict__ Cos, const float* __restrict__ mask_q,
                                                   const float* __restrict__ mask_d, const float* __restrict__ nn_scaler,
                                                   float* __restrict__ lp) {
    int wid = (blockIdx.x * 256 + threadIdx.x) >> 6;
    int lane = threadIdx.x & 63;
    int b = wid >> 6, qi = wid & 63;
    const float* crow = Cos + ((size_t)b * LQ + qi) * LD;
    const float* md = mask_d + b * LD;
    float acc[NK];
    #pragma unroll
    for (int k = 0; k < NK; k++) acc[k] = 0.f;
    #pragma unroll
    for (int r = 0; r < LD / 64; r++) {
        int dj = r * 64 + lane;
        float m = md[dj];
        if (m != 0.f) {
            float cv = crow[dj];
            #pragma unroll
            for (int k = 0; k < NK; k++) {
                float mu = (k == 0) ? 1.0f : (0.95f - 0.1f * (k - 1));
                float neg_inv = (k == 0) ? -500000.0f : -50.0f;
                float d = cv - mu;
                acc[k] += expf(d * d * neg_inv);
            }
        }
    }
    float mq = mask_q[b * LQ + qi];
    float ns = nn_scaler[0];
    #pragma unroll
    for (int k = 0; k < NK; k++) {
        float s = wave_sum(acc[k]);
        if (lane == 0) lp[((size_t)b * LQ + qi) * NK + k] = log2f(fmaxf(s, 1e-10f)) * ns * mq;
    }
}

// ---------------- final: out[b] = sum_k dense_w[k] * sum_qi lp[b,qi,k] ----------------
__global__ void final_kernel(const float* __restrict__ lp, const float* __restrict__ dense_w,
                             float* __restrict__ out) {
    int b = blockIdx.x;
    int t = threadIdx.x;  // 64 threads
    float s = 0.f;
    if (t < NK) {
        for (int qi = 0; qi < LQ; qi++) s += lp[((size_t)b * LQ + qi) * NK + t];
        s *= dense_w[t];
    }
    s = wave_sum(s);
    if (t == 0) out[b] = s;
}

extern "C" void kernel_launch(void* const* d_in, const int* in_sizes, int n_in,
                              void* d_out, int out_size, void* d_ws, size_t ws_size,
                              hipStream_t stream) {
    (void)in_sizes; (void)n_in; (void)out_size; (void)ws_size;
    const float* q_embed  = (const float*)d_in[0];
    const float* d_embed  = (const float*)d_in[1];
    const float* mask_q   = (const float*)d_in[2];
    const float* mask_d   = (const float*)d_in[3];
    const float* mixer    = (const float*)d_in[4];
    const float* nn_scaler= (const float*)d_in[5];
    const float* ff_w1    = (const float*)d_in[6];
    const float* ff_b1    = (const float*)d_in[7];
    const float* ff_w2    = (const float*)d_in[8];
    const float* ff_b2    = (const float*)d_in[9];
    const float* ln1_g    = (const float*)d_in[10];
    const float* ln1_b    = (const float*)d_in[11];
    const float* att_w    = (const float*)d_in[12];
    const float* att_b    = (const float*)d_in[13];
    const float* out_w    = (const float*)d_in[14];
    const float* out_b    = (const float*)d_in[15];
    const float* ln2_g    = (const float*)d_in[16];
    const float* ln2_b    = (const float*)d_in[17];
    const float* dense_w  = (const float*)d_in[18];
    float* out = (float*)d_out;

    // workspace layout (floats) — merged token stream: [q tokens (2048) | d tokens (16384)]
    float* ws   = (float*)d_ws;
    float* x    = ws;                      // MALL*300 = 5,529,600 (masked embeddings, persists)
    float* xc   = x   + (size_t)MALL * EMB; // 5,529,600 (encoder output / layer chain)
    float* t2   = xc  + (size_t)MALL * EMB; // 5,529,600
    float* hb   = t2  + (size_t)MALL * EMB; // 5,529,600
    float* t1cb = hb  + (size_t)MALL * EMB; // max(MALL*100, MALL*96) = 1,843,200
    float* o32  = t1cb + (size_t)MALL * FFH; // MALL*32 = 589,824
    float* mall = o32 + (size_t)MALL * ATTD; // 18,432
    // post-encoder aliases:
    float* qdn  = t2;                      // mixed+normalized tokens
    float* cosb = hb;                      // 32*64*512 = 1,048,576
    float* lp   = o32;                     // 32*64*21

    // 1. masked inputs (q segment then d segment) + mask concat
    maskmul_kernel<<<(MQ * EMB + 255) / 256, 256, 0, stream>>>(q_embed, mask_q, x, MQ * EMB);
    maskmul_kernel<<<(MD * EMB + 255) / 256, 256, 0, stream>>>(d_embed, mask_d, x + (size_t)MQ * EMB, MD * EMB);
    maskcat_kernel<<<(MALL + 255) / 256, 256, 0, stream>>>(mask_q, mask_d, mall);

    // 2. merged encoder (q+d share weights; attention splits by segment)
    const float* xcur = x;
    for (int l = 0; l < 2; l++) {
        gemm_nn<1><<<dim3(2, MALL / 32), 256, 0, stream>>>(xcur, ff_w1 + l * EMB * FFH, ff_b1 + l * FFH,
                                                           nullptr, t1cb, MALL, FFH, EMB);
        gemm_nn<2><<<dim3(5, MALL / 32), 256, 0, stream>>>(t1cb, ff_w2 + l * FFH * EMB, ff_b2 + l * EMB,
                                                           xcur, t2, MALL, EMB, FFH);
        ln_kernel<<<MALL / 4, 256, 0, stream>>>(t2, ln1_g + l * EMB, ln1_b + l * EMB, hb, MALL);
        gemm_nn<0><<<dim3(2, MALL / 32), 256, 0, stream>>>(hb, att_w + l * EMB * 96, att_b + l * 96,
                                                           nullptr, t1cb, MALL, 96, EMB);
        attn_fused<LQ, 64, 8><<<BATCH * NH, 512, 0, stream>>>(t1cb, mask_q, o32);
        attn_fused<LD, 128, 4><<<BATCH * NH * (LD / 128), 512, 0, stream>>>(
            t1cb + (size_t)MQ * 96, mask_d, o32 + (size_t)MQ * ATTD);
        gemm_nn<2><<<dim3(5, MALL / 32), 256, 0, stream>>>(o32, out_w + l * ATTD * EMB, out_b + l * EMB,
                                                           hb, t2, MALL, EMB, ATTD);
        ln_kernel<<<MALL / 4, 256, 0, stream>>>(t2, ln2_g + l * EMB, ln2_b + l * EMB, xc, MALL);
        xcur = xc;
    }

    // 3. mix + normalize (merged)
    mixnorm_kernel<<<MALL / 4, 256, 0, stream>>>(x, xc, mall, mixer, qdn);

    // 4. cosine matrix (q segment vs d segment of qdn)
    gemm_nt_cos<<<dim3(LD / 64, BATCH), 256, 0, stream>>>(qdn, qdn + (size_t)MQ * EMB, cosb);

    // 5. kernel pooling
    pool_kernel<<<(BATCH * LQ) / 4, 256, 0, stream>>>(cosb, mask_q, mask_d, nn_scaler, lp);

    // 6. final projection
    final_kernel<<<BATCH, 64, 0, stream>>>(lp, dense_w, out);
}